// Round 6
// baseline (266.176 us; speedup 1.0000x reference)
//
#include <hip/hip_runtime.h>

#define KDIM 1024

typedef _Float16 half8 __attribute__((ext_vector_type(8)));
typedef _Float16 half4 __attribute__((ext_vector_type(4)));
typedef __fp16 fp16x2 __attribute__((ext_vector_type(2)));
typedef __fp16 fp16x4 __attribute__((ext_vector_type(4)));
typedef float f32x4 __attribute__((ext_vector_type(4)));

#if defined(__has_builtin)
#if __has_builtin(__builtin_amdgcn_global_load_lds)
#define HAVE_GLDS 1
#endif
#if __has_builtin(__builtin_amdgcn_exp2f)
#define EXP2(x) __builtin_amdgcn_exp2f(x)
#endif
#if __has_builtin(__builtin_amdgcn_cvt_pkrtz)
#define HAVE_PKRTZ 1
#endif
#if __has_builtin(__builtin_amdgcn_fdot2)
#define HAVE_FDOT2 1
#endif
#endif
#ifndef EXP2
#define EXP2(x) exp2f(x)
#endif

__device__ __forceinline__ void stage16(const _Float16* g, _Float16* wave_base, int lane) {
#ifdef HAVE_GLDS
  __builtin_amdgcn_global_load_lds(
      (const __attribute__((address_space(1))) void*)g,
      (__attribute__((address_space(3))) void*)wave_base, 16, 0, 0);
#else
  *(half8*)(wave_base + lane * 8) = *(const half8*)g;
#endif
}

// ---------------- cast x (f32 -> f16), 4 elems/thread ----------------
__global__ void cast_x_kernel(const float* __restrict__ x, _Float16* __restrict__ xb) {
  size_t i = ((size_t)blockIdx.x * 256 + threadIdx.x) * 4;
  float4 v = *(const float4*)(x + i);
  half4 h = { (_Float16)v.x, (_Float16)v.y, (_Float16)v.z, (_Float16)v.w };
  *(half4*)(xb + i) = h;
}

// ------- transpose-cast weights into packed Wqkvt[3][n][k] -------
// Wq folded scale = log2(e)/8 so scores arrive in log2 domain.
__global__ void wtrans_kernel(const float* __restrict__ Wq, const float* __restrict__ Wk,
                              const float* __restrict__ Wv, _Float16* __restrict__ Wqkvt) {
  int z = blockIdx.z;
  const float* src = z == 0 ? Wq : (z == 1 ? Wk : Wv);
  _Float16* dst = Wqkvt + (size_t)z * KDIM * KDIM;
  float sc = (z == 0) ? 0.18033688011112042f : 1.0f;  // (1/8)*log2(e)
  __shared__ _Float16 tile[32][33];
  int tx = threadIdx.x & 31, ty = threadIdx.x >> 5;
  int c0 = blockIdx.x * 32, r0 = blockIdx.y * 32;
#pragma unroll
  for (int i = 0; i < 4; i++) {
    int r = r0 + ty + i * 8;
    tile[tx][ty + i * 8] = (_Float16)(src[(size_t)r * KDIM + c0 + tx] * sc);
  }
  __syncthreads();
#pragma unroll
  for (int i = 0; i < 4; i++) {
    int n = c0 + ty + i * 8;
    dst[(size_t)n * KDIM + r0 + tx] = tile[ty + i * 8][tx];
  }
}

// ---------------- mask -> bitmask (1 bit per (b,q,t), t fastest) ----------------
__global__ void maskbits_kernel(const float* __restrict__ m, unsigned long long* __restrict__ bits) {
  size_t i = (size_t)blockIdx.x * 256 + threadIdx.x;
  unsigned long long b = __ballot(m[i] != 0.0f);
  if ((threadIdx.x & 63) == 0) bits[i >> 6] = b;
}

// ------------- fused QKV GEMM: C[M=8192][N=3072] = xb * Wqkvt^T -------------
__global__ __launch_bounds__(256, 2)
void gemm_kernel(const _Float16* __restrict__ A, const _Float16* __restrict__ Bt,
                 _Float16* __restrict__ Qt, _Float16* __restrict__ Kh,
                 _Float16* __restrict__ Vth) {
  __shared__ _Float16 As[128 * 32];
  __shared__ _Float16 Bs[128 * 32];
  int tid = threadIdx.x;
  int lane = tid & 63, w4 = tid >> 6;
  int la = lane & 15, qd = lane >> 4;
  int wm = w4 & 1, wn = w4 >> 1;
  int m0 = blockIdx.y * 128, n0 = blockIdx.x * 128;
  int r = tid >> 2, c = (tid & 3) * 8;
  const _Float16* Ag = A + (size_t)(m0 + r) * KDIM + c;
  const _Float16* Bg = Bt + (size_t)(n0 + r) * KDIM + c;
  _Float16* a0 = As + w4 * 512;
  _Float16* b0 = Bs + w4 * 512;
  f32x4 acc[4][4] = {};
  for (int kt = 0; kt < KDIM; kt += 32) {
    stage16(Ag + kt, a0, lane);
    stage16(Ag + (size_t)64 * KDIM + kt, a0 + 2048, lane);
    stage16(Bg + kt, b0, lane);
    stage16(Bg + (size_t)64 * KDIM + kt, b0 + 2048, lane);
    __syncthreads();
    half8 af[4], bf[4];
#pragma unroll
    for (int mi = 0; mi < 4; mi++)
      af[mi] = *(const half8*)(As + (wm * 64 + mi * 16 + la) * 32 + qd * 8);
#pragma unroll
    for (int ni = 0; ni < 4; ni++)
      bf[ni] = *(const half8*)(Bs + (wn * 64 + ni * 16 + la) * 32 + qd * 8);
#pragma unroll
    for (int mi = 0; mi < 4; mi++)
#pragma unroll
      for (int ni = 0; ni < 4; ni++)
        acc[mi][ni] = __builtin_amdgcn_mfma_f32_16x16x32_f16(af[mi], bf[ni], acc[mi][ni], 0, 0, 0);
    __syncthreads();
  }
  int which = n0 >> 10;                 // 0:Q 1:K 2:V (uniform per block)
  int hh = ((n0 + wn * 64) >> 6) & 15;  // uniform per wave
  int mbase = m0 + wm * 64;
  int b = mbase >> 10, s0 = mbase & 1023;
  if (which == 1) {
#pragma unroll
    for (int mi = 0; mi < 4; mi++)
#pragma unroll
      for (int ni = 0; ni < 4; ni++) {
        f32x4 v = acc[mi][ni];
        int s = s0 + mi * 16 + qd * 4;
        int d = ni * 16 + la;
#pragma unroll
        for (int rg = 0; rg < 4; rg++)
          Kh[(((size_t)(b * 16 + hh)) * 1024 + s + rg) * 64 + d] = (_Float16)v[rg];
      }
  } else {
    _Float16* dst = (which == 0) ? Qt : Vth;
    // wave-private transpose patch: 16 rows x 72 halves (bank-perfect both ways)
    _Float16* ep = (w4 < 2) ? (As + w4 * 2048) : (Bs + (w4 - 2) * 2048);
    _Float16* base = dst + ((size_t)(b * 16 + hh)) * 64 * 1024;
    int rr = lane >> 2, c4 = lane & 3;
#pragma unroll
    for (int ni = 0; ni < 4; ni++) {
#pragma unroll
      for (int mi = 0; mi < 4; mi++) {
        f32x4 v = acc[mi][ni];
        half4 hv = { (_Float16)v[0], (_Float16)v[1], (_Float16)v[2], (_Float16)v[3] };
        *(half4*)(ep + la * 72 + mi * 16 + qd * 4) = hv;  // row=d(la), col=s
      }
      half8 o0 = *(const half8*)(ep + rr * 72 + c4 * 16);
      half8 o1 = *(const half8*)(ep + rr * 72 + c4 * 16 + 8);
      _Float16* gp = base + (size_t)(ni * 16 + rr) * 1024 + s0 + c4 * 16;
      *(half8*)gp = o0;
      *(half8*)(gp + 8) = o1;
    }
  }
}

// ---------------- fused attention ----------------
// 512 threads = 8 waves, 128 q-rows per block; grid 1024 XCD-swizzled.
// S^T = K*Q^T via 16x16x32 (C-layout == A-frag of 16x16x16), exp2 in-register
// (log2e folded into Wq), PV via 16x16x16. Vs rows padded to 40 halves.
__global__ __launch_bounds__(512, 2)
void attn_kernel(const _Float16* __restrict__ Qt, const _Float16* __restrict__ K,
                 const _Float16* __restrict__ Vt, const unsigned long long* __restrict__ mbits,
                 float* __restrict__ out) {
  __shared__ _Float16 Ks[2 * 64 * 32];  // [ks=d/32][t][32], one block-wide stage16
  __shared__ _Float16 Vs[2 * 64 * 40];  // [tc=t/32][d][40 padded]
  int tid = threadIdx.x;
  int lane = tid & 63, w4 = tid >> 6;  // w4 0..7
  int la = lane & 15, qd = lane >> 4;
  // swizzle: linear = ((hb/8)*8 + qt)*8 + hb%8 -> same (b,h) shares an XCD
  int linear = blockIdx.x;
  int xlo = linear & 7;
  int tmp = linear >> 3;
  int qt = tmp & 7;
  int hb = (tmp >> 3) * 8 + xlo;
  int h = hb & 15, b = hb >> 4;
  const _Float16* Qp = Qt + ((size_t)(b * 16 + h)) * 64 * 1024;  // [d][s]
  const _Float16* Kp = K + ((size_t)(b * 16 + h)) * 1024 * 64;   // [s][d]
  const _Float16* Vp = Vt + ((size_t)(b * 16 + h)) * 64 * 1024;  // [d][s]
  int q0w = qt * 128 + w4 * 16;
  // Q B-frag (one-time): qf[ks][j] = Q[q=q0w+la][d=ks*32+qd*8+j]
  half8 qf[2];
#pragma unroll
  for (int ks = 0; ks < 2; ks++)
#pragma unroll
    for (int j = 0; j < 8; j++)
      qf[ks][j] = Qp[(size_t)(ks * 32 + qd * 8 + j) * 1024 + q0w + la];
  // mask preload: 4 u64 (32B coalesced) per lane covers all 16 t-tiles
  unsigned long long mq[4];
  {
    const ulonglong2* mp =
        (const ulonglong2*)(mbits + ((size_t)b * 1024 + q0w + la) * 16 + qd * 4);
    ulonglong2 m01 = mp[0];
    ulonglong2 m23 = mp[1];
    mq[0] = m01.x; mq[1] = m01.y; mq[2] = m23.x; mq[3] = m23.y;
  }
  f32x4 acco[4] = {};
  float rs = 0.0f;
  // K staging map: one block-wide stage16 covers the whole 64x64 tile
  int kt_t = (tid & 255) >> 2;
  int kt_d = (tid >> 8) * 32 + (tid & 3) * 8;
  _Float16* kbase = Ks + w4 * 512;  // wave-uniform; linear idx = tid*8
  // V staging map: lane reads 8 consecutive s for one d
  int vd = tid >> 3;
  int vt = (tid & 7) * 8;
  _Float16* vdst = Vs + (vt >= 32 ? 2560 : 0) + vd * 40 + (vt & 31);
#ifdef HAVE_FDOT2
  fp16x2 one2 = { (__fp16)1.0f, (__fp16)1.0f };
#endif
  for (int tt = 0; tt < 16; tt++) {
    half8 vv = *(const half8*)(Vp + (size_t)vd * 1024 + tt * 64 + vt);
    stage16(Kp + (size_t)(tt * 64 + kt_t) * 64 + kt_d, kbase, lane);
    *(half8*)vdst = vv;
    __syncthreads();
    // S^T tiles: D[t' = qd*4+rg][q = la], A = K-frag, B = Q-frag
    f32x4 accs[4] = {};
#pragma unroll
    for (int tsub = 0; tsub < 4; tsub++)
#pragma unroll
      for (int ks = 0; ks < 2; ks++) {
        half8 kf = *(const half8*)(Ks + ks * 2048 + (tsub * 16 + la) * 32 + qd * 8);
        accs[tsub] = __builtin_amdgcn_mfma_f32_16x16x32_f16(kf, qf[ks], accs[tsub], 0, 0, 0);
      }
    unsigned long long mw = __shfl(mq[tt & 3], ((tt >> 2) << 4) + la);
#pragma unroll
    for (int tsub = 0; tsub < 4; tsub++) {
      float e0 = ((mw >> (tsub * 16 + qd * 4 + 0)) & 1ull) ? EXP2(accs[tsub][0]) : 0.0f;
      float e1 = ((mw >> (tsub * 16 + qd * 4 + 1)) & 1ull) ? EXP2(accs[tsub][1]) : 0.0f;
      float e2 = ((mw >> (tsub * 16 + qd * 4 + 2)) & 1ull) ? EXP2(accs[tsub][2]) : 0.0f;
      float e3 = ((mw >> (tsub * 16 + qd * 4 + 3)) & 1ull) ? EXP2(accs[tsub][3]) : 0.0f;
      half4 pf;
#ifdef HAVE_PKRTZ
      fp16x2 p01 = __builtin_amdgcn_cvt_pkrtz(e0, e1);
      fp16x2 p23 = __builtin_amdgcn_cvt_pkrtz(e2, e3);
      fp16x4 pfv = __builtin_shufflevector(p01, p23, 0, 1, 2, 3);
      pf = __builtin_bit_cast(half4, pfv);
#else
      pf[0] = (_Float16)e0; pf[1] = (_Float16)e1; pf[2] = (_Float16)e2; pf[3] = (_Float16)e3;
#endif
#if defined(HAVE_FDOT2) && defined(HAVE_PKRTZ)
      rs = __builtin_amdgcn_fdot2(p01, one2, rs, false);
      rs = __builtin_amdgcn_fdot2(p23, one2, rs, false);
#else
      rs += e0 + e1 + e2 + e3;
#endif
#pragma unroll
      for (int nsub = 0; nsub < 4; nsub++) {
        half4 vf = *(const half4*)(Vs + (tsub >> 1) * 2560 + (nsub * 16 + la) * 40 +
                                   (tsub & 1) * 16 + qd * 4);
        acco[nsub] = __builtin_amdgcn_mfma_f32_16x16x16f16(pf, vf, acco[nsub], 0, 0, 0);
      }
    }
    __syncthreads();
  }
  rs += __shfl_xor(rs, 16);
  rs += __shfl_xor(rs, 32);
  float inv_q = 1.0f / (rs + 1e-8f);
  float* op = out + (size_t)b * 1024 * 1024 + (size_t)h * 64;
#pragma unroll
  for (int rg = 0; rg < 4; rg++) {
    float inv = __shfl(inv_q, qd * 4 + rg);
    int s = q0w + qd * 4 + rg;
#pragma unroll
    for (int nsub = 0; nsub < 4; nsub++)
      op[(size_t)s * 1024 + nsub * 16 + la] = acco[nsub][rg] * inv;
  }
}

extern "C" void kernel_launch(void* const* d_in, const int* in_sizes, int n_in,
                              void* d_out, int out_size, void* d_ws, size_t ws_size,
                              hipStream_t stream) {
  (void)in_sizes; (void)n_in; (void)out_size; (void)ws_size;
  const float* x = (const float*)d_in[0];
  const float* am = (const float*)d_in[1];
  const float* Wq = (const float*)d_in[2];
  const float* Wk = (const float*)d_in[3];
  const float* Wv = (const float*)d_in[4];
  float* out = (float*)d_out;

  char* p = (char*)d_ws;
  _Float16* xb = (_Float16*)p;    p += (size_t)8192 * 1024 * 2;
  _Float16* Wqkvt = (_Float16*)p; p += (size_t)3 * 1024 * 1024 * 2;
  _Float16* Qt = (_Float16*)p;    p += (size_t)8192 * 1024 * 2;   // [b,h,d,s]
  _Float16* Kh = (_Float16*)p;    p += (size_t)8192 * 1024 * 2;   // [b,h,s,d]
  _Float16* Vth = (_Float16*)p;   p += (size_t)8192 * 1024 * 2;   // [b,h,d,s]
  unsigned long long* mb = (unsigned long long*)p;

  cast_x_kernel<<<8192, 256, 0, stream>>>(x, xb);
  wtrans_kernel<<<dim3(32, 32, 3), 256, 0, stream>>>(Wq, Wk, Wv, Wqkvt);
  maskbits_kernel<<<32768, 256, 0, stream>>>(am, mb);
  gemm_kernel<<<dim3(24, 64), 256, 0, stream>>>(xb, Wqkvt, Qt, Kh, Vth);
  attn_kernel<<<1024, 512, 0, stream>>>(Qt, Kh, Vth, mb, out);
}

// Round 7
// 263.371 us; speedup vs baseline: 1.0106x; 1.0106x over previous
//
#include <hip/hip_runtime.h>

#define KDIM 1024

typedef _Float16 half8 __attribute__((ext_vector_type(8)));
typedef _Float16 half4 __attribute__((ext_vector_type(4)));
typedef __fp16 fp16x2 __attribute__((ext_vector_type(2)));
typedef __fp16 fp16x4 __attribute__((ext_vector_type(4)));
typedef float f32x4 __attribute__((ext_vector_type(4)));

#if defined(__has_builtin)
#if __has_builtin(__builtin_amdgcn_global_load_lds)
#define HAVE_GLDS 1
#endif
#if __has_builtin(__builtin_amdgcn_exp2f)
#define EXP2(x) __builtin_amdgcn_exp2f(x)
#endif
#if __has_builtin(__builtin_amdgcn_cvt_pkrtz)
#define HAVE_PKRTZ 1
#endif
#if __has_builtin(__builtin_amdgcn_fdot2)
#define HAVE_FDOT2 1
#endif
#endif
#ifndef EXP2
#define EXP2(x) exp2f(x)
#endif

__device__ __forceinline__ void stage16(const _Float16* g, _Float16* wave_base, int lane) {
#ifdef HAVE_GLDS
  __builtin_amdgcn_global_load_lds(
      (const __attribute__((address_space(1))) void*)g,
      (__attribute__((address_space(3))) void*)wave_base, 16, 0, 0);
#else
  *(half8*)(wave_base + lane * 8) = *(const half8*)g;
#endif
}

// ---------------- cast x (f32 -> f16), 4 elems/thread ----------------
__global__ void cast_x_kernel(const float* __restrict__ x, _Float16* __restrict__ xb) {
  size_t i = ((size_t)blockIdx.x * 256 + threadIdx.x) * 4;
  float4 v = *(const float4*)(x + i);
  half4 h = { (_Float16)v.x, (_Float16)v.y, (_Float16)v.z, (_Float16)v.w };
  *(half4*)(xb + i) = h;
}

// ------- transpose-cast weights into packed Wqkvt[3][n][k] -------
// Wq folded scale = log2(e)/8 so scores arrive in log2 domain.
__global__ void wtrans_kernel(const float* __restrict__ Wq, const float* __restrict__ Wk,
                              const float* __restrict__ Wv, _Float16* __restrict__ Wqkvt) {
  int z = blockIdx.z;
  const float* src = z == 0 ? Wq : (z == 1 ? Wk : Wv);
  _Float16* dst = Wqkvt + (size_t)z * KDIM * KDIM;
  float sc = (z == 0) ? 0.18033688011112042f : 1.0f;  // (1/8)*log2(e)
  __shared__ _Float16 tile[32][33];
  int tx = threadIdx.x & 31, ty = threadIdx.x >> 5;
  int c0 = blockIdx.x * 32, r0 = blockIdx.y * 32;
#pragma unroll
  for (int i = 0; i < 4; i++) {
    int r = r0 + ty + i * 8;
    tile[tx][ty + i * 8] = (_Float16)(src[(size_t)r * KDIM + c0 + tx] * sc);
  }
  __syncthreads();
#pragma unroll
  for (int i = 0; i < 4; i++) {
    int n = c0 + ty + i * 8;
    dst[(size_t)n * KDIM + r0 + tx] = tile[ty + i * 8][tx];
  }
}

// ---------------- mask -> bitmask (1 bit per (b,q,t), t fastest) ----------------
__global__ void maskbits_kernel(const float* __restrict__ m, unsigned long long* __restrict__ bits) {
  size_t i = (size_t)blockIdx.x * 256 + threadIdx.x;
  unsigned long long b = __ballot(m[i] != 0.0f);
  if ((threadIdx.x & 63) == 0) bits[i >> 6] = b;
}

// ------------- fused QKV GEMM: C[M=8192][N=3072] = xb * Wqkvt^T -------------
__global__ __launch_bounds__(256, 2)
void gemm_kernel(const _Float16* __restrict__ A, const _Float16* __restrict__ Bt,
                 _Float16* __restrict__ Qt, _Float16* __restrict__ Kh,
                 _Float16* __restrict__ Vth) {
  __shared__ _Float16 As[128 * 32];
  __shared__ _Float16 Bs[128 * 32];
  int tid = threadIdx.x;
  int lane = tid & 63, w4 = tid >> 6;
  int la = lane & 15, qd = lane >> 4;
  int wm = w4 & 1, wn = w4 >> 1;
  int m0 = blockIdx.y * 128, n0 = blockIdx.x * 128;
  int r = tid >> 2, c = (tid & 3) * 8;
  const _Float16* Ag = A + (size_t)(m0 + r) * KDIM + c;
  const _Float16* Bg = Bt + (size_t)(n0 + r) * KDIM + c;
  _Float16* a0 = As + w4 * 512;
  _Float16* b0 = Bs + w4 * 512;
  f32x4 acc[4][4] = {};
  for (int kt = 0; kt < KDIM; kt += 32) {
    stage16(Ag + kt, a0, lane);
    stage16(Ag + (size_t)64 * KDIM + kt, a0 + 2048, lane);
    stage16(Bg + kt, b0, lane);
    stage16(Bg + (size_t)64 * KDIM + kt, b0 + 2048, lane);
    __syncthreads();
    half8 af[4], bf[4];
#pragma unroll
    for (int mi = 0; mi < 4; mi++)
      af[mi] = *(const half8*)(As + (wm * 64 + mi * 16 + la) * 32 + qd * 8);
#pragma unroll
    for (int ni = 0; ni < 4; ni++)
      bf[ni] = *(const half8*)(Bs + (wn * 64 + ni * 16 + la) * 32 + qd * 8);
#pragma unroll
    for (int mi = 0; mi < 4; mi++)
#pragma unroll
      for (int ni = 0; ni < 4; ni++)
        acc[mi][ni] = __builtin_amdgcn_mfma_f32_16x16x32_f16(af[mi], bf[ni], acc[mi][ni], 0, 0, 0);
    __syncthreads();
  }
  int which = n0 >> 10;                 // 0:Q 1:K 2:V (uniform per block)
  int hh = ((n0 + wn * 64) >> 6) & 15;  // uniform per wave
  int mbase = m0 + wm * 64;
  int b = mbase >> 10, s0 = mbase & 1023;
  if (which == 1) {
#pragma unroll
    for (int mi = 0; mi < 4; mi++)
#pragma unroll
      for (int ni = 0; ni < 4; ni++) {
        f32x4 v = acc[mi][ni];
        int s = s0 + mi * 16 + qd * 4;
        int d = ni * 16 + la;
#pragma unroll
        for (int rg = 0; rg < 4; rg++)
          Kh[(((size_t)(b * 16 + hh)) * 1024 + s + rg) * 64 + d] = (_Float16)v[rg];
      }
  } else {
    _Float16* dst = (which == 0) ? Qt : Vth;
    // wave-private transpose patch: 16 rows x 72 halves (bank-perfect both ways)
    _Float16* ep = (w4 < 2) ? (As + w4 * 2048) : (Bs + (w4 - 2) * 2048);
    _Float16* base = dst + ((size_t)(b * 16 + hh)) * 64 * 1024;
    int rr = lane >> 2, c4 = lane & 3;
#pragma unroll
    for (int ni = 0; ni < 4; ni++) {
#pragma unroll
      for (int mi = 0; mi < 4; mi++) {
        f32x4 v = acc[mi][ni];
        half4 hv = { (_Float16)v[0], (_Float16)v[1], (_Float16)v[2], (_Float16)v[3] };
        *(half4*)(ep + la * 72 + mi * 16 + qd * 4) = hv;  // row=d(la), col=s
      }
      half8 o0 = *(const half8*)(ep + rr * 72 + c4 * 16);
      half8 o1 = *(const half8*)(ep + rr * 72 + c4 * 16 + 8);
      _Float16* gp = base + (size_t)(ni * 16 + rr) * 1024 + s0 + c4 * 16;
      *(half8*)gp = o0;
      *(half8*)(gp + 8) = o1;
    }
  }
}

// ---------------- fused attention ----------------
// 512 threads = 8 waves; each wave owns TWO 16-row Q-fragments (128 apart)
// => 256 q-rows/block, grid 512 XCD-swizzled. kf/vf LDS fragment reads are
// shared across both Q-frags (halves LDS bytes per q-row — the R6 limiter).
__global__ __launch_bounds__(512, 2)
void attn_kernel(const _Float16* __restrict__ Qt, const _Float16* __restrict__ K,
                 const _Float16* __restrict__ Vt, const unsigned long long* __restrict__ mbits,
                 float* __restrict__ out) {
  __shared__ _Float16 Ks[2 * 64 * 32];  // [ks=d/32][t][32], one block-wide stage16
  __shared__ _Float16 Vs[2 * 64 * 40];  // [tc=t/32][d][40 padded]
  int tid = threadIdx.x;
  int lane = tid & 63, w4 = tid >> 6;  // w4 0..7
  int la = lane & 15, qd = lane >> 4;
  // swizzle: 512 blocks; same hb -> same XCD (blockIdx%8)
  int linear = blockIdx.x;
  int xlo = linear & 7;
  int tmp = linear >> 3;  // 0..63
  int qt = tmp & 3;
  int hb = (tmp >> 2) * 8 + xlo;  // 0..127
  int h = hb & 15, b = hb >> 4;
  const _Float16* Qp = Qt + (size_t)hb * 64 * 1024;  // [d][s]
  const _Float16* Kp = K + (size_t)hb * 1024 * 64;   // [s][d]
  const _Float16* Vp = Vt + (size_t)hb * 64 * 1024;  // [d][s]
  int q0w = qt * 256 + w4 * 16;  // qfrag qi adds qi*128
  // Q B-frags (one-time): qf[qi][ks][j] = Q[q=q0w+qi*128+la][d=ks*32+qd*8+j]
  half8 qf[2][2];
#pragma unroll
  for (int qi = 0; qi < 2; qi++)
#pragma unroll
    for (int ks = 0; ks < 2; ks++)
#pragma unroll
      for (int j = 0; j < 8; j++)
        qf[qi][ks][j] = Qp[(size_t)(ks * 32 + qd * 8 + j) * 1024 + q0w + qi * 128 + la];
  // mask preload: per qfrag, 4 u64 (32B coalesced) covers all 16 t-tiles
  unsigned long long mq[2][4];
#pragma unroll
  for (int qi = 0; qi < 2; qi++) {
    const ulonglong2* mp =
        (const ulonglong2*)(mbits + ((size_t)b * 1024 + q0w + qi * 128 + la) * 16 + qd * 4);
    ulonglong2 m01 = mp[0];
    ulonglong2 m23 = mp[1];
    mq[qi][0] = m01.x; mq[qi][1] = m01.y; mq[qi][2] = m23.x; mq[qi][3] = m23.y;
  }
  f32x4 acco[2][4] = {};
  float rs[2] = {0.f, 0.f};
  // K staging: one block-wide stage16 covers the 64x64 tile
  int kt_t = (tid & 255) >> 2;
  int kt_d = (tid >> 8) * 32 + (tid & 3) * 8;
  _Float16* kbase = Ks + w4 * 512;
  // V staging: lane reads 8 consecutive s for one d
  int vd = tid >> 3;
  int vt = (tid & 7) * 8;
  _Float16* vdst = Vs + (vt >= 32 ? 2560 : 0) + vd * 40 + (vt & 31);
#if defined(HAVE_FDOT2) && defined(HAVE_PKRTZ)
  fp16x2 one2 = { (__fp16)1.0f, (__fp16)1.0f };
#endif
  for (int tt = 0; tt < 16; tt++) {
    half8 vv = *(const half8*)(Vp + (size_t)vd * 1024 + tt * 64 + vt);
    stage16(Kp + (size_t)(tt * 64 + kt_t) * 64 + kt_d, kbase, lane);
    *(half8*)vdst = vv;
    __syncthreads();
    unsigned long long mw0 = __shfl(mq[0][tt & 3], ((tt >> 2) << 4) + la);
    unsigned long long mw1 = __shfl(mq[1][tt & 3], ((tt >> 2) << 4) + la);
#pragma unroll
    for (int tsub = 0; tsub < 4; tsub++) {
      // kf loaded once, used by both qfrags (S^T: D[t'=qd*4+rg][q=la])
      half8 kf0 = *(const half8*)(Ks + (tsub * 16 + la) * 32 + qd * 8);
      half8 kf1 = *(const half8*)(Ks + 2048 + (tsub * 16 + la) * 32 + qd * 8);
      f32x4 a0 = {}, a1 = {};
      a0 = __builtin_amdgcn_mfma_f32_16x16x32_f16(kf0, qf[0][0], a0, 0, 0, 0);
      a1 = __builtin_amdgcn_mfma_f32_16x16x32_f16(kf0, qf[1][0], a1, 0, 0, 0);
      a0 = __builtin_amdgcn_mfma_f32_16x16x32_f16(kf1, qf[0][1], a0, 0, 0, 0);
      a1 = __builtin_amdgcn_mfma_f32_16x16x32_f16(kf1, qf[1][1], a1, 0, 0, 0);
      half4 pf[2];
#pragma unroll
      for (int qi = 0; qi < 2; qi++) {
        const f32x4& aa = qi ? a1 : a0;
        unsigned long long mw = qi ? mw1 : mw0;
        float e0 = ((mw >> (tsub * 16 + qd * 4 + 0)) & 1ull) ? EXP2(aa[0]) : 0.0f;
        float e1 = ((mw >> (tsub * 16 + qd * 4 + 1)) & 1ull) ? EXP2(aa[1]) : 0.0f;
        float e2 = ((mw >> (tsub * 16 + qd * 4 + 2)) & 1ull) ? EXP2(aa[2]) : 0.0f;
        float e3 = ((mw >> (tsub * 16 + qd * 4 + 3)) & 1ull) ? EXP2(aa[3]) : 0.0f;
#ifdef HAVE_PKRTZ
        fp16x2 p01 = __builtin_amdgcn_cvt_pkrtz(e0, e1);
        fp16x2 p23 = __builtin_amdgcn_cvt_pkrtz(e2, e3);
        fp16x4 pfv = __builtin_shufflevector(p01, p23, 0, 1, 2, 3);
        pf[qi] = __builtin_bit_cast(half4, pfv);
#else
        pf[qi][0] = (_Float16)e0; pf[qi][1] = (_Float16)e1;
        pf[qi][2] = (_Float16)e2; pf[qi][3] = (_Float16)e3;
#endif
#if defined(HAVE_FDOT2) && defined(HAVE_PKRTZ)
        rs[qi] = __builtin_amdgcn_fdot2(p01, one2, rs[qi], false);
        rs[qi] = __builtin_amdgcn_fdot2(p23, one2, rs[qi], false);
#else
        rs[qi] += e0 + e1 + e2 + e3;
#endif
      }
#pragma unroll
      for (int nsub = 0; nsub < 4; nsub++) {
        // vf loaded once, used by both qfrags
        half4 vf = *(const half4*)(Vs + (tsub >> 1) * 2560 + (nsub * 16 + la) * 40 +
                                   (tsub & 1) * 16 + qd * 4);
        acco[0][nsub] = __builtin_amdgcn_mfma_f32_16x16x16f16(pf[0], vf, acco[0][nsub], 0, 0, 0);
        acco[1][nsub] = __builtin_amdgcn_mfma_f32_16x16x16f16(pf[1], vf, acco[1][nsub], 0, 0, 0);
      }
    }
    __syncthreads();
  }
  float* op = out + (size_t)b * 1024 * 1024 + (size_t)h * 64;
#pragma unroll
  for (int qi = 0; qi < 2; qi++) {
    float r0 = rs[qi];
    r0 += __shfl_xor(r0, 16);
    r0 += __shfl_xor(r0, 32);
    float inv_q = 1.0f / (r0 + 1e-8f);
#pragma unroll
    for (int rg = 0; rg < 4; rg++) {
      float inv = __shfl(inv_q, qd * 4 + rg);
      int s = q0w + qi * 128 + qd * 4 + rg;
#pragma unroll
      for (int nsub = 0; nsub < 4; nsub++)
        op[(size_t)s * 1024 + nsub * 16 + la] = acco[qi][nsub][rg] * inv;
    }
  }
}

extern "C" void kernel_launch(void* const* d_in, const int* in_sizes, int n_in,
                              void* d_out, int out_size, void* d_ws, size_t ws_size,
                              hipStream_t stream) {
  (void)in_sizes; (void)n_in; (void)out_size; (void)ws_size;
  const float* x = (const float*)d_in[0];
  const float* am = (const float*)d_in[1];
  const float* Wq = (const float*)d_in[2];
  const float* Wk = (const float*)d_in[3];
  const float* Wv = (const float*)d_in[4];
  float* out = (float*)d_out;

  char* p = (char*)d_ws;
  _Float16* xb = (_Float16*)p;    p += (size_t)8192 * 1024 * 2;
  _Float16* Wqkvt = (_Float16*)p; p += (size_t)3 * 1024 * 1024 * 2;
  _Float16* Qt = (_Float16*)p;    p += (size_t)8192 * 1024 * 2;   // [b,h,d,s]
  _Float16* Kh = (_Float16*)p;    p += (size_t)8192 * 1024 * 2;   // [b,h,s,d]
  _Float16* Vth = (_Float16*)p;   p += (size_t)8192 * 1024 * 2;   // [b,h,d,s]
  unsigned long long* mb = (unsigned long long*)p;

  cast_x_kernel<<<8192, 256, 0, stream>>>(x, xb);
  wtrans_kernel<<<dim3(32, 32, 3), 256, 0, stream>>>(Wq, Wk, Wv, Wqkvt);
  maskbits_kernel<<<32768, 256, 0, stream>>>(am, mb);
  gemm_kernel<<<dim3(24, 64), 256, 0, stream>>>(xb, Wqkvt, Qt, Kh, Vth);
  attn_kernel<<<512, 512, 0, stream>>>(Qt, Kh, Vth, mb, out);
}

// Round 8
// 251.619 us; speedup vs baseline: 1.0579x; 1.0467x over previous
//
#include <hip/hip_runtime.h>

#define KDIM 1024

typedef _Float16 half8 __attribute__((ext_vector_type(8)));
typedef _Float16 half4 __attribute__((ext_vector_type(4)));
typedef __fp16 fp16x2 __attribute__((ext_vector_type(2)));
typedef __fp16 fp16x4 __attribute__((ext_vector_type(4)));
typedef float f32x4 __attribute__((ext_vector_type(4)));

#if defined(__has_builtin)
#if __has_builtin(__builtin_amdgcn_global_load_lds)
#define HAVE_GLDS 1
#endif
#if __has_builtin(__builtin_amdgcn_exp2f)
#define EXP2(x) __builtin_amdgcn_exp2f(x)
#endif
#if __has_builtin(__builtin_amdgcn_cvt_pkrtz)
#define HAVE_PKRTZ 1
#endif
#if __has_builtin(__builtin_amdgcn_fdot2)
#define HAVE_FDOT2 1
#endif
#endif
#ifndef EXP2
#define EXP2(x) exp2f(x)
#endif

__device__ __forceinline__ void stage16(const _Float16* g, _Float16* wave_base, int lane) {
#ifdef HAVE_GLDS
  __builtin_amdgcn_global_load_lds(
      (const __attribute__((address_space(1))) void*)g,
      (__attribute__((address_space(3))) void*)wave_base, 16, 0, 0);
#else
  *(half8*)(wave_base + lane * 8) = *(const half8*)g;
#endif
}

// ------------- merged prep: cast x | transpose-cast W | mask bits -------------
// blocks [0,8192): cast x f32->f16, 4 elems/thread
// blocks [8192,11264): wtrans (z = (bid-8192)/1024), Wq scaled by log2(e)/8
// blocks [11264,44032): maskbits
__global__ void prep_kernel(const float* __restrict__ x, const float* __restrict__ am,
                            const float* __restrict__ Wq, const float* __restrict__ Wk,
                            const float* __restrict__ Wv, _Float16* __restrict__ xb,
                            _Float16* __restrict__ Wqkvt, unsigned long long* __restrict__ bits) {
  __shared__ _Float16 tile[32][33];
  int bid = blockIdx.x;
  if (bid < 8192) {
    size_t i = ((size_t)bid * 256 + threadIdx.x) * 4;
    float4 v = *(const float4*)(x + i);
    half4 h = { (_Float16)v.x, (_Float16)v.y, (_Float16)v.z, (_Float16)v.w };
    *(half4*)(xb + i) = h;
  } else if (bid < 11264) {
    int zz = bid - 8192;
    int z = zz >> 10;
    int rem = zz & 1023;
    int bx = rem & 31, by = rem >> 5;
    const float* src = z == 0 ? Wq : (z == 1 ? Wk : Wv);
    _Float16* dst = Wqkvt + (size_t)z * KDIM * KDIM;
    float sc = (z == 0) ? 0.18033688011112042f : 1.0f;  // (1/8)*log2(e)
    int tx = threadIdx.x & 31, ty = threadIdx.x >> 5;
    int c0 = bx * 32, r0 = by * 32;
#pragma unroll
    for (int i = 0; i < 4; i++) {
      int r = r0 + ty + i * 8;
      tile[tx][ty + i * 8] = (_Float16)(src[(size_t)r * KDIM + c0 + tx] * sc);
    }
    __syncthreads();
#pragma unroll
    for (int i = 0; i < 4; i++) {
      int n = c0 + ty + i * 8;
      dst[(size_t)n * KDIM + r0 + tx] = tile[ty + i * 8][tx];
    }
  } else {
    size_t i = (size_t)(bid - 11264) * 256 + threadIdx.x;
    unsigned long long b = __ballot(am[i] != 0.0f);
    if ((threadIdx.x & 63) == 0) bits[i >> 6] = b;
  }
}

// ------------- fused QKV GEMM: C[M=8192][N=3072] = xb * Wqkvt^T -------------
__global__ __launch_bounds__(256, 2)
void gemm_kernel(const _Float16* __restrict__ A, const _Float16* __restrict__ Bt,
                 _Float16* __restrict__ Qt, _Float16* __restrict__ Kh,
                 _Float16* __restrict__ Vth) {
  __shared__ _Float16 As[128 * 32];
  __shared__ _Float16 Bs[128 * 32];
  int tid = threadIdx.x;
  int lane = tid & 63, w4 = tid >> 6;
  int la = lane & 15, qd = lane >> 4;
  int wm = w4 & 1, wn = w4 >> 1;
  int m0 = blockIdx.y * 128, n0 = blockIdx.x * 128;
  int r = tid >> 2, c = (tid & 3) * 8;
  const _Float16* Ag = A + (size_t)(m0 + r) * KDIM + c;
  const _Float16* Bg = Bt + (size_t)(n0 + r) * KDIM + c;
  _Float16* a0 = As + w4 * 512;
  _Float16* b0 = Bs + w4 * 512;
  f32x4 acc[4][4] = {};
  for (int kt = 0; kt < KDIM; kt += 32) {
    stage16(Ag + kt, a0, lane);
    stage16(Ag + (size_t)64 * KDIM + kt, a0 + 2048, lane);
    stage16(Bg + kt, b0, lane);
    stage16(Bg + (size_t)64 * KDIM + kt, b0 + 2048, lane);
    __syncthreads();
    half8 af[4], bf[4];
#pragma unroll
    for (int mi = 0; mi < 4; mi++)
      af[mi] = *(const half8*)(As + (wm * 64 + mi * 16 + la) * 32 + qd * 8);
#pragma unroll
    for (int ni = 0; ni < 4; ni++)
      bf[ni] = *(const half8*)(Bs + (wn * 64 + ni * 16 + la) * 32 + qd * 8);
#pragma unroll
    for (int mi = 0; mi < 4; mi++)
#pragma unroll
      for (int ni = 0; ni < 4; ni++)
        acc[mi][ni] = __builtin_amdgcn_mfma_f32_16x16x32_f16(af[mi], bf[ni], acc[mi][ni], 0, 0, 0);
    __syncthreads();
  }
  int which = n0 >> 10;                 // 0:Q 1:K 2:V (uniform per block)
  int hh = ((n0 + wn * 64) >> 6) & 15;  // uniform per wave
  int mbase = m0 + wm * 64;
  int b = mbase >> 10, s0 = mbase & 1023;
  if (which == 1) {
#pragma unroll
    for (int mi = 0; mi < 4; mi++)
#pragma unroll
      for (int ni = 0; ni < 4; ni++) {
        f32x4 v = acc[mi][ni];
        int s = s0 + mi * 16 + qd * 4;
        int d = ni * 16 + la;
#pragma unroll
        for (int rg = 0; rg < 4; rg++)
          Kh[(((size_t)(b * 16 + hh)) * 1024 + s + rg) * 64 + d] = (_Float16)v[rg];
      }
  } else {
    _Float16* dst = (which == 0) ? Qt : Vth;
    // wave-private transpose patch: 16 rows x 72 halves (bank-perfect both ways)
    _Float16* ep = (w4 < 2) ? (As + w4 * 2048) : (Bs + (w4 - 2) * 2048);
    _Float16* base = dst + ((size_t)(b * 16 + hh)) * 64 * 1024;
    int rr = lane >> 2, c4 = lane & 3;
#pragma unroll
    for (int ni = 0; ni < 4; ni++) {
#pragma unroll
      for (int mi = 0; mi < 4; mi++) {
        f32x4 v = acc[mi][ni];
        half4 hv = { (_Float16)v[0], (_Float16)v[1], (_Float16)v[2], (_Float16)v[3] };
        *(half4*)(ep + la * 72 + mi * 16 + qd * 4) = hv;  // row=d(la), col=s
      }
      half8 o0 = *(const half8*)(ep + rr * 72 + c4 * 16);
      half8 o1 = *(const half8*)(ep + rr * 72 + c4 * 16 + 8);
      _Float16* gp = base + (size_t)(ni * 16 + rr) * 1024 + s0 + c4 * 16;
      *(half8*)gp = o0;
      *(half8*)(gp + 8) = o1;
    }
  }
}

// ---------------- fused attention ----------------
// 512 threads = 8 waves; each wave owns TWO 16-row Q-fragments; 256 q-rows/blk.
// Double-buffered K/V tiles: stage tt+1 at top, compute tt, ONE barrier/tile —
// staging latency overlaps compute instead of draining at a post-stage barrier.
__global__ __launch_bounds__(512, 2)
void attn_kernel(const _Float16* __restrict__ Qt, const _Float16* __restrict__ K,
                 const _Float16* __restrict__ Vt, const unsigned long long* __restrict__ mbits,
                 float* __restrict__ out) {
  __shared__ _Float16 Ks[2][2 * 64 * 32];  // [buf][ks=d/32][t][32]
  __shared__ _Float16 Vs[2][2 * 64 * 40];  // [buf][tc=t/32][d][40 padded]
  int tid = threadIdx.x;
  int lane = tid & 63, w4 = tid >> 6;  // w4 0..7
  int la = lane & 15, qd = lane >> 4;
  // swizzle: 512 blocks; same hb -> same XCD (blockIdx%8)
  int linear = blockIdx.x;
  int xlo = linear & 7;
  int tmp = linear >> 3;  // 0..63
  int qt = tmp & 3;
  int hb = (tmp >> 2) * 8 + xlo;  // 0..127
  int h = hb & 15, b = hb >> 4;
  const _Float16* Qp = Qt + (size_t)hb * 64 * 1024;  // [d][s]
  const _Float16* Kp = K + (size_t)hb * 1024 * 64;   // [s][d]
  const _Float16* Vp = Vt + (size_t)hb * 64 * 1024;  // [d][s]
  int q0w = qt * 256 + w4 * 16;  // qfrag qi adds qi*128
  // Q B-frags (one-time): qf[qi][ks][j] = Q[q=q0w+qi*128+la][d=ks*32+qd*8+j]
  half8 qf[2][2];
#pragma unroll
  for (int qi = 0; qi < 2; qi++)
#pragma unroll
    for (int ks = 0; ks < 2; ks++)
#pragma unroll
      for (int j = 0; j < 8; j++)
        qf[qi][ks][j] = Qp[(size_t)(ks * 32 + qd * 8 + j) * 1024 + q0w + qi * 128 + la];
  // mask preload: per qfrag, 4 u64 (32B coalesced) covers all 16 t-tiles
  unsigned long long mq[2][4];
#pragma unroll
  for (int qi = 0; qi < 2; qi++) {
    const ulonglong2* mp =
        (const ulonglong2*)(mbits + ((size_t)b * 1024 + q0w + qi * 128 + la) * 16 + qd * 4);
    ulonglong2 m01 = mp[0];
    ulonglong2 m23 = mp[1];
    mq[qi][0] = m01.x; mq[qi][1] = m01.y; mq[qi][2] = m23.x; mq[qi][3] = m23.y;
  }
  f32x4 acco[2][4] = {};
  float rs[2] = {0.f, 0.f};
  // K staging: block-wide stage16 covers the 64x64 tile (LDS linear = tid*8)
  int kt_t = (tid & 255) >> 2;
  int kt_d = (tid >> 8) * 32 + (tid & 3) * 8;
  // V staging: lane reads 8 consecutive s for one d
  int vd = tid >> 3;
  int vt = (tid & 7) * 8;
  int vs_off = (vt >= 32 ? 2560 : 0) + vd * 40 + (vt & 31);
#if defined(HAVE_FDOT2) && defined(HAVE_PKRTZ)
  fp16x2 one2 = { (__fp16)1.0f, (__fp16)1.0f };
#endif
  // prologue: stage tile 0 into buf 0
  {
    stage16(Kp + (size_t)kt_t * 64 + kt_d, Ks[0] + w4 * 512, lane);
    half8 vv = *(const half8*)(Vp + (size_t)vd * 1024 + vt);
    *(half8*)(Vs[0] + vs_off) = vv;
  }
  __syncthreads();
  for (int tt = 0; tt < 16; tt++) {
    int cur = tt & 1, nxt = cur ^ 1;
    half8 vvn;
    if (tt < 15) {
      vvn = *(const half8*)(Vp + (size_t)vd * 1024 + (tt + 1) * 64 + vt);
      stage16(Kp + (size_t)((tt + 1) * 64 + kt_t) * 64 + kt_d, Ks[nxt] + w4 * 512, lane);
    }
    const _Float16* ks_ = Ks[cur];
    const _Float16* vs_ = Vs[cur];
    unsigned long long mw0 = __shfl(mq[0][tt & 3], ((tt >> 2) << 4) + la);
    unsigned long long mw1 = __shfl(mq[1][tt & 3], ((tt >> 2) << 4) + la);
#pragma unroll
    for (int tsub = 0; tsub < 4; tsub++) {
      // kf loaded once, used by both qfrags (S^T: D[t'=qd*4+rg][q=la])
      half8 kf0 = *(const half8*)(ks_ + (tsub * 16 + la) * 32 + qd * 8);
      half8 kf1 = *(const half8*)(ks_ + 2048 + (tsub * 16 + la) * 32 + qd * 8);
      f32x4 a0 = {}, a1 = {};
      a0 = __builtin_amdgcn_mfma_f32_16x16x32_f16(kf0, qf[0][0], a0, 0, 0, 0);
      a1 = __builtin_amdgcn_mfma_f32_16x16x32_f16(kf0, qf[1][0], a1, 0, 0, 0);
      a0 = __builtin_amdgcn_mfma_f32_16x16x32_f16(kf1, qf[0][1], a0, 0, 0, 0);
      a1 = __builtin_amdgcn_mfma_f32_16x16x32_f16(kf1, qf[1][1], a1, 0, 0, 0);
      half4 pf[2];
#pragma unroll
      for (int qi = 0; qi < 2; qi++) {
        const f32x4& aa = qi ? a1 : a0;
        unsigned long long mw = qi ? mw1 : mw0;
        float e0 = ((mw >> (tsub * 16 + qd * 4 + 0)) & 1ull) ? EXP2(aa[0]) : 0.0f;
        float e1 = ((mw >> (tsub * 16 + qd * 4 + 1)) & 1ull) ? EXP2(aa[1]) : 0.0f;
        float e2 = ((mw >> (tsub * 16 + qd * 4 + 2)) & 1ull) ? EXP2(aa[2]) : 0.0f;
        float e3 = ((mw >> (tsub * 16 + qd * 4 + 3)) & 1ull) ? EXP2(aa[3]) : 0.0f;
#ifdef HAVE_PKRTZ
        fp16x2 p01 = __builtin_amdgcn_cvt_pkrtz(e0, e1);
        fp16x2 p23 = __builtin_amdgcn_cvt_pkrtz(e2, e3);
        fp16x4 pfv = __builtin_shufflevector(p01, p23, 0, 1, 2, 3);
        pf[qi] = __builtin_bit_cast(half4, pfv);
#else
        pf[qi][0] = (_Float16)e0; pf[qi][1] = (_Float16)e1;
        pf[qi][2] = (_Float16)e2; pf[qi][3] = (_Float16)e3;
#endif
#if defined(HAVE_FDOT2) && defined(HAVE_PKRTZ)
        rs[qi] = __builtin_amdgcn_fdot2(p01, one2, rs[qi], false);
        rs[qi] = __builtin_amdgcn_fdot2(p23, one2, rs[qi], false);
#else
        rs[qi] += e0 + e1 + e2 + e3;
#endif
      }
#pragma unroll
      for (int nsub = 0; nsub < 4; nsub++) {
        half4 vf = *(const half4*)(vs_ + (tsub >> 1) * 2560 + (nsub * 16 + la) * 40 +
                                   (tsub & 1) * 16 + qd * 4);
        acco[0][nsub] = __builtin_amdgcn_mfma_f32_16x16x16f16(pf[0], vf, acco[0][nsub], 0, 0, 0);
        acco[1][nsub] = __builtin_amdgcn_mfma_f32_16x16x16f16(pf[1], vf, acco[1][nsub], 0, 0, 0);
      }
    }
    if (tt < 15) *(half8*)(Vs[nxt] + vs_off) = vvn;
    __syncthreads();
  }
  float* op = out + (size_t)b * 1024 * 1024 + (size_t)h * 64;
#pragma unroll
  for (int qi = 0; qi < 2; qi++) {
    float r0 = rs[qi];
    r0 += __shfl_xor(r0, 16);
    r0 += __shfl_xor(r0, 32);
    float inv_q = 1.0f / (r0 + 1e-8f);
#pragma unroll
    for (int rg = 0; rg < 4; rg++) {
      float inv = __shfl(inv_q, qd * 4 + rg);
      int s = q0w + qi * 128 + qd * 4 + rg;
#pragma unroll
      for (int nsub = 0; nsub < 4; nsub++)
        op[(size_t)s * 1024 + nsub * 16 + la] = acco[qi][nsub][rg] * inv;
    }
  }
}

extern "C" void kernel_launch(void* const* d_in, const int* in_sizes, int n_in,
                              void* d_out, int out_size, void* d_ws, size_t ws_size,
                              hipStream_t stream) {
  (void)in_sizes; (void)n_in; (void)out_size; (void)ws_size;
  const float* x = (const float*)d_in[0];
  const float* am = (const float*)d_in[1];
  const float* Wq = (const float*)d_in[2];
  const float* Wk = (const float*)d_in[3];
  const float* Wv = (const float*)d_in[4];
  float* out = (float*)d_out;

  char* p = (char*)d_ws;
  _Float16* xb = (_Float16*)p;    p += (size_t)8192 * 1024 * 2;
  _Float16* Wqkvt = (_Float16*)p; p += (size_t)3 * 1024 * 1024 * 2;
  _Float16* Qt = (_Float16*)p;    p += (size_t)8192 * 1024 * 2;   // [b,h,d,s]
  _Float16* Kh = (_Float16*)p;    p += (size_t)8192 * 1024 * 2;   // [b,h,s,d]
  _Float16* Vth = (_Float16*)p;   p += (size_t)8192 * 1024 * 2;   // [b,h,d,s]
  unsigned long long* mb = (unsigned long long*)p;

  prep_kernel<<<44032, 256, 0, stream>>>(x, am, Wq, Wk, Wv, xb, Wqkvt, mb);
  gemm_kernel<<<dim3(24, 64), 256, 0, stream>>>(xb, Wqkvt, Qt, Kh, Vth);
  attn_kernel<<<512, 512, 0, stream>>>(Qt, Kh, Vth, mb, out);
}